// Round 26
// baseline (70.221 us; speedup 1.0000x reference)
//
#include <hip/hip_runtime.h>
#include <hip/hip_bf16.h>

// Problem constants
#define Bb 4
#define Ll 2048
#define Dd 1024
#define DKk 64
#define BL (Bb*Ll)
#define G_SPLIT 8   // split of the s-range across blocks in attention
#define NMW 11      // mask tasks per wave (6144 waves cover 65536 tasks)

typedef __attribute__((ext_vector_type(4))) float f32x4;
typedef __attribute__((ext_vector_type(8))) short bf16x8;

__device__ __forceinline__ unsigned short f2bf(float x) {
  unsigned int u = __builtin_bit_cast(unsigned int, x);
  u += 0x7fffu + ((u >> 16) & 1u);   // RNE
  return (unsigned short)(u >> 16);
}
__device__ __forceinline__ unsigned int pack2bf(float a, float b) {
  return (unsigned int)f2bf(a) | ((unsigned int)f2bf(b) << 16);
}

// ---------------------------------------------------------------------------
// prep: Wfq/Wfk/Wfv in MFMA-B-fragment order:
//   n = t*16+lr, k = ks*32 + g*8 + e  ->  flat ((ks*4+t)*4+g)*128 + lr*8 + e
// WoSumT[1024d][64k] bf16 with WoSum[k][d] = sum_h Wo[h*64+k][d].
// ---------------------------------------------------------------------------
__global__ __launch_bounds__(256)
void prep_kernel(const float* __restrict__ Wq, const float* __restrict__ Wk,
                 const float* __restrict__ Wv, const float* __restrict__ Wo,
                 unsigned short* __restrict__ Wfq, unsigned short* __restrict__ Wfk,
                 unsigned short* __restrict__ Wfv, unsigned short* __restrict__ WoSumT) {
  int idx = blockIdx.x * 256 + threadIdx.x;
  if (idx < 3 * 65536) {
    int which = idx >> 16;
    int r = idx & 65535;
    int n = r & 63, k = r >> 6;   // consecutive threads -> consecutive n (coalesced read)
    const float* W = which == 0 ? Wq : (which == 1 ? Wk : Wv);
    unsigned short* Wf = which == 0 ? Wfq : (which == 1 ? Wfk : Wfv);
    const int t = n >> 4, lr = n & 15;
    const int ks = k >> 5, g = (k >> 3) & 3, e = k & 7;
    Wf[(size_t)(((ks * 4 + t) * 4 + g) * 128) + lr * 8 + e] = f2bf(W[(size_t)k * 64 + n]);
  } else {
    int r = idx - 3 * 65536;
    int d = r & 1023, k = r >> 10;
    float s = 0.f;
#pragma unroll
    for (int h = 0; h < 16; ++h) s += Wo[(size_t)(h * 64 + k) * 1024 + d];
    WoSumT[(size_t)d * 64 + k] = f2bf(s);
  }
}

// ---------------------------------------------------------------------------
// projmask v5 (T14 async-split for the mask stream): 1536 blocks, ALL proj
// role. Prologue issues NMW=11 independent int4 mask loads per thread (held
// in statically-indexed registers, no consumer until epilogue) -> their HBM
// latency is absorbed by the single barrier drain of the proj stage. The
// one-shot proj (R15/R23 internals) is unchanged. Epilogue does the ballots
// + BM writes on long-arrived data. No dedicated mask blocks -> proj keeps
// every CU slot.
// ---------------------------------------------------------------------------
__global__ __launch_bounds__(256)
void projmask_kernel(const float* __restrict__ query, const float* __restrict__ key,
                     const float* __restrict__ value,
                     const unsigned short* __restrict__ Wfq, const unsigned short* __restrict__ Wfk,
                     const unsigned short* __restrict__ Wfv,
                     const int* __restrict__ mask, unsigned long long* __restrict__ BM,
                     unsigned short* __restrict__ Qp, unsigned short* __restrict__ Kf,
                     unsigned short* __restrict__ Vf) {
  __shared__ __align__(16) unsigned short Xl[16 * 1032];

  const int tid = threadIdx.x;
  const int which = blockIdx.x >> 9;
  const float* X = which == 0 ? query : (which == 1 ? key : value);
  const unsigned short* Wf = which == 0 ? Wfq : (which == 1 ? Wfk : Wfv);
  const int R0 = (blockIdx.x & 511) * 16;

  const int w = tid >> 6, lane = tid & 63;
  const int g = lane >> 4, lr = lane & 15;
  const int wid = blockIdx.x * 4 + w;       // 0..6143

  // ---- mask prologue: issue NMW independent loads, hold in registers ----
  int4 mreg[NMW];
#pragma unroll
  for (int j = 0; j < NMW; ++j) {
    int task = wid + j * 6144;
    int ct = task < BL * 8 ? task : 0;      // clamp (safe duplicate read)
    mreg[j] = *(const int4*)(mask + (size_t)ct * 256 + lane * 4);
  }

  // ---- proj: one-shot stage ----
  f32x4 xr[16];
#pragma unroll
  for (int i = 0; i < 8; ++i) {
    int c = tid + 256 * i;
    int row = c >> 7, kc = c & 127;
    const float* src = X + (size_t)(R0 + row) * 1024 + kc * 8;
    xr[2 * i] = *(const f32x4*)src;
    xr[2 * i + 1] = *(const f32x4*)(src + 4);
  }
#pragma unroll
  for (int i = 0; i < 8; ++i) {
    int c = tid + 256 * i;
    int row = c >> 7, kc = c & 127;
    uint4 p;
    p.x = pack2bf(xr[2 * i][0], xr[2 * i][1]);
    p.y = pack2bf(xr[2 * i][2], xr[2 * i][3]);
    p.z = pack2bf(xr[2 * i + 1][0], xr[2 * i + 1][1]);
    p.w = pack2bf(xr[2 * i + 1][2], xr[2 * i + 1][3]);
    *(uint4*)&Xl[row * 1032 + kc * 8] = p;
  }
  __syncthreads();   // vmcnt(0) drain here also covers the mask loads (one stall)

  f32x4 acc0 = (f32x4){0.f, 0.f, 0.f, 0.f};
  f32x4 acc1 = (f32x4){0.f, 0.f, 0.f, 0.f};
  const unsigned short* xrow = &Xl[lr * 1032 + g * 8];
  const unsigned short* wfb = Wf + (size_t)(w * 4 + g) * 128 + lr * 8;
#pragma unroll
  for (int ks = 0; ks < 32; ks += 2) {
    bf16x8 a0 = *(const bf16x8*)(xrow + ks * 32);
    bf16x8 b0 = *(const bf16x8*)(wfb + (size_t)ks * 2048);
    acc0 = __builtin_amdgcn_mfma_f32_16x16x32_bf16(a0, b0, acc0, 0, 0, 0);
    bf16x8 a1 = *(const bf16x8*)(xrow + (ks + 1) * 32);
    bf16x8 b1 = *(const bf16x8*)(wfb + (size_t)(ks + 1) * 2048);
    acc1 = __builtin_amdgcn_mfma_f32_16x16x32_bf16(a1, b1, acc1, 0, 0, 0);
  }
  f32x4 acc = acc0 + acc1;

  const int dk = w * 16 + lr;
  if (which == 0) {
#pragma unroll
    for (int i = 0; i < 4; ++i)
      Qp[(size_t)(R0 + 4 * g + i) * 64 + dk] = f2bf(acc[i]);
  } else if (which == 1) {
#pragma unroll
    for (int i = 0; i < 4; ++i) {
      const int sg = R0 + 4 * g + i;
      const int b = sg >> 11, sl = sg & 2047;
      const int tile = b * 32 + (sl >> 6), c = (sl >> 4) & 3, lrk = sl & 15;
      Kf[(size_t)tile * 4096 + (c * 8 + (dk >> 3)) * 128 + lrk * 8 + (dk & 7)] = f2bf(acc[i]);
    }
  } else {
#pragma unroll
    for (int i = 0; i < 4; ++i) {
      const int sg = R0 + 4 * g + i;
      const int b = sg >> 11, sl = sg & 2047;
      const int tile = b * 32 + (sl >> 6);
      const int h = (sl >> 5) & 1, g2 = (sl >> 3) & 3, e2 = sl & 7;
      Vf[(size_t)tile * 4096 + ((w * 2 + h) * 4 + g2) * 128 + lr * 8 + e2] = f2bf(acc[i]);
    }
  }

  // ---- mask epilogue: ballots + BM writes (data long since arrived) ----
#pragma unroll
  for (int j = 0; j < NMW; ++j) {
    const int task = wid + j * 6144;
    if (task < BL * 8) {                    // wave-uniform predicate
      unsigned long long c0 = __ballot(mreg[j].x != 0);
      unsigned long long c1 = __ballot(mreg[j].y != 0);
      unsigned long long c2 = __ballot(mreg[j].z != 0);
      unsigned long long c3 = __ballot(mreg[j].w != 0);
      unsigned long long v = lane == 0 ? c0 : lane == 1 ? c1 : lane == 2 ? c2 : c3;
      if (lane < 4) BM[(size_t)task * 4 + lane] = v;
    }
  }
}

// ---------------------------------------------------------------------------
// attn: no LDS, no barriers, all fragment loads coalesced; mask via bitmask.
// Opart stored in FRAGMENT ORDER: [T][t][lane][4] f32, T = gy*512 + bx*2 + w.
// Lane (g,lr)'s o[t][i] = element (row q = T*16+lr, col dk = t*16+g*4+i).
// grid (BL/32, G_SPLIT) = 2048 blocks, 128 thr.
// ---------------------------------------------------------------------------
__global__ __launch_bounds__(128, 4)
void attn_kernel(const unsigned short* __restrict__ Qp, const unsigned short* __restrict__ Kf,
                 const unsigned short* __restrict__ Vf, const unsigned long long* __restrict__ BM,
                 float* __restrict__ Opart, float* __restrict__ lpart) {
  const int q0 = blockIdx.x * 32;
  const int gy = blockIdx.y;
  const int b = q0 >> 11;
  const int tid = threadIdx.x, lane = tid & 63, w = tid >> 6;
  const int g = lane >> 4, lr = lane & 15;

  const unsigned short* qrow = Qp + (size_t)(q0 + w * 16 + lr) * 64;
  bf16x8 qf0 = *(const bf16x8*)(qrow + g * 8);
  bf16x8 qf1 = *(const bf16x8*)(qrow + 32 + g * 8);

  const unsigned long long* bm = BM + ((size_t)(q0 + w * 16 + lr) * 8 + gy) * 4;
  const unsigned long long W0 = bm[0], W1 = bm[1], W2 = bm[2], W3 = bm[3];

  f32x4 o[4];
#pragma unroll
  for (int t = 0; t < 4; ++t) o[t] = (f32x4){0.f, 0.f, 0.f, 0.f};
  float lsum = 0.f;

  const unsigned short* Kt = Kf + (size_t)(b * 32 + gy * 4) * 4096;
  const unsigned short* Vt = Vf + (size_t)(b * 32 + gy * 4) * 4096;

#pragma unroll
  for (int st = 0; st < 4; ++st) {
    const unsigned short* Kts = Kt + st * 4096;
    const unsigned short* Vts = Vt + st * 4096;

    bf16x8 kf0[4], kf1[4];
#pragma unroll
    for (int c = 0; c < 4; ++c) {
      kf0[c] = *(const bf16x8*)(Kts + (c * 8 + g) * 128 + lr * 8);
      kf1[c] = *(const bf16x8*)(Kts + (c * 8 + 4 + g) * 128 + lr * 8);
    }

    uint2 packs[4];
#pragma unroll
    for (int c = 0; c < 4; ++c) {
      f32x4 a4 = (f32x4){0.f, 0.f, 0.f, 0.f};
      a4 = __builtin_amdgcn_mfma_f32_16x16x32_bf16(kf0[c], qf0, a4, 0, 0, 0);
      a4 = __builtin_amdgcn_mfma_f32_16x16x32_bf16(kf1[c], qf1, a4, 0, 0, 0);
      const int j = st * 16 + 4 * c + g;
      float p0 = ((W0 >> j) & 1) ? __expf(a4[0] * 0.125f) : 0.f;
      float p1 = ((W1 >> j) & 1) ? __expf(a4[1] * 0.125f) : 0.f;
      float p2 = ((W2 >> j) & 1) ? __expf(a4[2] * 0.125f) : 0.f;
      float p3 = ((W3 >> j) & 1) ? __expf(a4[3] * 0.125f) : 0.f;
      lsum += (p0 + p1) + (p2 + p3);
      packs[c].x = pack2bf(p0, p1);
      packs[c].y = pack2bf(p2, p3);
    }

#pragma unroll
    for (int h = 0; h < 2; ++h) {
      const int srcLo = lr + ((g & 1) << 5);
      const int srcHi = srcLo + 16;
      uint2 pl0 = packs[2 * h], pl1 = packs[2 * h + 1];
      unsigned a0x = __shfl((int)pl0.x, srcLo), a0y = __shfl((int)pl0.y, srcLo);
      unsigned a1x = __shfl((int)pl1.x, srcLo), a1y = __shfl((int)pl1.y, srcLo);
      unsigned b0x = __shfl((int)pl0.x, srcHi), b0y = __shfl((int)pl0.y, srcHi);
      unsigned b1x = __shfl((int)pl1.x, srcHi), b1y = __shfl((int)pl1.y, srcHi);
      const bool hisel = ((g >> 1) & 1) != 0;
      uint4 bb;
      bb.x = hisel ? a1x : a0x;
      bb.y = hisel ? a1y : a0y;
      bb.z = hisel ? b1x : b0x;
      bb.w = hisel ? b1y : b0y;
      bf16x8 pb = __builtin_bit_cast(bf16x8, bb);
#pragma unroll
      for (int t = 0; t < 4; ++t) {
        bf16x8 av = *(const bf16x8*)(Vts + ((t * 2 + h) * 4 + g) * 128 + lr * 8);
        o[t] = __builtin_amdgcn_mfma_f32_16x16x32_bf16(av, pb, o[t], 0, 0, 0);
      }
    }
  }

  lsum += __shfl_xor(lsum, 16);
  lsum += __shfl_xor(lsum, 32);

  // fragment-ordered store: T = gy*512 + bx*2 + w; [T][t][lane][4] f32
  float* Ob = Opart + ((size_t)(gy * 512 + blockIdx.x * 2 + w) * 4) * 256;
#pragma unroll
  for (int t = 0; t < 4; ++t)
    *(f32x4*)(Ob + (t * 256) + lane * 4) = o[t];
  if (lane < 16)
    lpart[(size_t)gy * BL + q0 + w * 16 + lane] = lsum;
}

// ---------------------------------------------------------------------------
// oproj (combine fused): builds the Hp tile in-LDS from fragment-ordered
// Opart (tile r holds row q = r*16+lr, cols dk = t*16+g*4+i) + lpart
// normalization, then the usual MFMA.
// grid (128 m-tiles, 4 n-tiles of 256), 256 thr.
// ---------------------------------------------------------------------------
__global__ __launch_bounds__(256)
void oproj_kernel(const float* __restrict__ Opart, const float* __restrict__ lpart,
                  const unsigned short* __restrict__ WoSumT, float* __restrict__ out) {
  const int R0 = blockIdx.x * 64;
  const int n0 = blockIdx.y * 256;
  __shared__ __align__(16) unsigned short Hl[64 * 72];
  __shared__ __align__(16) unsigned short Wl[256 * 72];
  const int tid = threadIdx.x, lane = tid & 63, w = tid >> 6;
  const int g = lane >> 4, lr = lane & 15;

#pragma unroll
  for (int i = 0; i < 8; ++i) {
    int c = tid + 256 * i;
    int row = c >> 3, cc = c & 7;
    *(uint4*)&Wl[row * 72 + cc * 8] = *(const uint4*)(WoSumT + (size_t)(n0 + row) * 64 + cc * 8);
  }

  {
    const int t = w;
#pragma unroll
    for (int j = 0; j < 4; ++j) {
      const int rg = (R0 >> 4) + j;           // global tile, rows rg*16..+15
      const int q = rg * 16 + lr;
      f32x4 s = (f32x4){0.f, 0.f, 0.f, 0.f};
      float l = 0.f;
#pragma unroll
      for (int gg = 0; gg < G_SPLIT; ++gg) {
        f32x4 a = *(const f32x4*)(Opart + ((size_t)((gg * 512 + rg) * 4 + t)) * 256 + lane * 4);
        s[0] += a[0]; s[1] += a[1]; s[2] += a[2]; s[3] += a[3];
        l += lpart[(size_t)gg * BL + q];
      }
      const float inv = 1.f / l;
      uint2 pv;
      pv.x = pack2bf(s[0] * inv, s[1] * inv);
      pv.y = pack2bf(s[2] * inv, s[3] * inv);
      *(uint2*)&Hl[(j * 16 + lr) * 72 + t * 16 + g * 4] = pv;
    }
  }
  __syncthreads();

  f32x4 acc[16];
#pragma unroll
  for (int t = 0; t < 16; ++t) acc[t] = (f32x4){0.f, 0.f, 0.f, 0.f};
#pragma unroll
  for (int kh = 0; kh < 2; ++kh) {
    bf16x8 a = *(const bf16x8*)&Hl[(w * 16 + lr) * 72 + kh * 32 + g * 8];
#pragma unroll
    for (int t = 0; t < 16; ++t) {
      bf16x8 bb = *(const bf16x8*)&Wl[(t * 16 + lr) * 72 + kh * 32 + g * 8];
      acc[t] = __builtin_amdgcn_mfma_f32_16x16x32_bf16(a, bb, acc[t], 0, 0, 0);
    }
  }
  float* ob = out + (size_t)(R0 + w * 16 + g * 4) * 1024 + n0 + lr;
#pragma unroll
  for (int t = 0; t < 16; ++t)
#pragma unroll
    for (int i = 0; i < 4; ++i)
      ob[(size_t)i * 1024 + t * 16] = acc[t][i];
}

// ---------------------------------------------------------------------------
extern "C" void kernel_launch(void* const* d_in, const int* in_sizes, int n_in,
                              void* d_out, int out_size, void* d_ws, size_t ws_size,
                              hipStream_t stream) {
  const float* query = (const float*)d_in[0];
  const float* key   = (const float*)d_in[1];
  const float* value = (const float*)d_in[2];
  const int*   mask  = (const int*)d_in[3];
  const float* Wq    = (const float*)d_in[4];
  const float* Wk    = (const float*)d_in[5];
  const float* Wv    = (const float*)d_in[6];
  const float* Wo    = (const float*)d_in[7];
  float* out = (float*)d_out;

  unsigned short* Qp   = (unsigned short*)d_ws;           // 8192*64
  unsigned short* Kf   = Qp + (size_t)BL * 64;            // 8192*64 (fragment order)
  unsigned short* Vf   = Kf + (size_t)BL * 64;            // 8192*64 (fragment order)
  unsigned short* Wfq  = Vf + (size_t)BL * 64;            // 64*1024 (fragment order)
  unsigned short* Wfk  = Wfq + 65536;
  unsigned short* Wfv  = Wfk + 65536;
  unsigned short* WoSumT = Wfv + 65536;                   // 1024*64
  float* lpart = (float*)(WoSumT + 65536);                // G*8192
  float* Opart = lpart + (size_t)G_SPLIT * BL;            // G*8192*64 fp32 (fragment order)
  unsigned long long* BM = (unsigned long long*)(Opart + (size_t)G_SPLIT * BL * 64); // 2MB

  hipLaunchKernelGGL(prep_kernel, dim3(1024), dim3(256), 0, stream,
                     Wq, Wk, Wv, Wo, Wfq, Wfk, Wfv, WoSumT);
  hipLaunchKernelGGL(projmask_kernel, dim3(1536), dim3(256), 0, stream,
                     query, key, value, Wfq, Wfk, Wfv, mask, BM, Qp, Kf, Vf);
  hipLaunchKernelGGL(attn_kernel, dim3(BL / 32, G_SPLIT), dim3(128), 0, stream,
                     Qp, Kf, Vf, BM, Opart, lpart);
  hipLaunchKernelGGL(oproj_kernel, dim3(128, 4), dim3(256), 0, stream,
                     Opart, lpart, WoSumT, out);
}

// Round 27
// 67.491 us; speedup vs baseline: 1.0405x; 1.0405x over previous
//
#include <hip/hip_runtime.h>
#include <hip/hip_bf16.h>

// Problem constants
#define Bb 4
#define Ll 2048
#define Dd 1024
#define DKk 64
#define BL (Bb*Ll)
#define G_SPLIT 8   // split of the s-range across blocks in attention

typedef __attribute__((ext_vector_type(4))) float f32x4;
typedef __attribute__((ext_vector_type(8))) short bf16x8;

__device__ __forceinline__ unsigned short f2bf(float x) {
  unsigned int u = __builtin_bit_cast(unsigned int, x);
  u += 0x7fffu + ((u >> 16) & 1u);   // RNE
  return (unsigned short)(u >> 16);
}
__device__ __forceinline__ unsigned int pack2bf(float a, float b) {
  return (unsigned int)f2bf(a) | ((unsigned int)f2bf(b) << 16);
}

// ---------------------------------------------------------------------------
// prep: Wfq/Wfk/Wfv in MFMA-B-fragment order:
//   n = t*16+lr, k = ks*32 + g*8 + e  ->  flat ((ks*4+t)*4+g)*128 + lr*8 + e
// WoSumT[1024d][64k] bf16 with WoSum[k][d] = sum_h Wo[h*64+k][d].
// ---------------------------------------------------------------------------
__global__ __launch_bounds__(256)
void prep_kernel(const float* __restrict__ Wq, const float* __restrict__ Wk,
                 const float* __restrict__ Wv, const float* __restrict__ Wo,
                 unsigned short* __restrict__ Wfq, unsigned short* __restrict__ Wfk,
                 unsigned short* __restrict__ Wfv, unsigned short* __restrict__ WoSumT) {
  int idx = blockIdx.x * 256 + threadIdx.x;
  if (idx < 3 * 65536) {
    int which = idx >> 16;
    int r = idx & 65535;
    int n = r & 63, k = r >> 6;   // consecutive threads -> consecutive n (coalesced read)
    const float* W = which == 0 ? Wq : (which == 1 ? Wk : Wv);
    unsigned short* Wf = which == 0 ? Wfq : (which == 1 ? Wfk : Wfv);
    const int t = n >> 4, lr = n & 15;
    const int ks = k >> 5, g = (k >> 3) & 3, e = k & 7;
    Wf[(size_t)(((ks * 4 + t) * 4 + g) * 128) + lr * 8 + e] = f2bf(W[(size_t)k * 64 + n]);
  } else {
    int r = idx - 3 * 65536;
    int d = r & 1023, k = r >> 10;
    float s = 0.f;
#pragma unroll
    for (int h = 0; h < 16; ++h) s += Wo[(size_t)(h * 64 + k) * 1024 + d];
    WoSumT[(size_t)d * 64 + k] = f2bf(s);
  }
}

// ---------------------------------------------------------------------------
// projmask (best measured config): blocks 0..511 stream-compress the mask
// into the 2MB bitmask; blocks 512..2047 run the one-shot proj.
// ---------------------------------------------------------------------------
__global__ __launch_bounds__(256)
void projmask_kernel(const float* __restrict__ query, const float* __restrict__ key,
                     const float* __restrict__ value,
                     const unsigned short* __restrict__ Wfq, const unsigned short* __restrict__ Wfk,
                     const unsigned short* __restrict__ Wfv,
                     const int* __restrict__ mask, unsigned long long* __restrict__ BM,
                     unsigned short* __restrict__ Qp, unsigned short* __restrict__ Kf,
                     unsigned short* __restrict__ Vf) {
  __shared__ __align__(16) unsigned short Xl[16 * 1032];  // proj branch only

  const int tid = threadIdx.x;

  if (blockIdx.x < 512) {
    const int wid = (blockIdx.x * 256 + tid) >> 6;
    const int lane = tid & 63;
    for (int task = wid; task < BL * 8; task += 2048) {
      const int4 m = *(const int4*)(mask + (size_t)task * 256 + lane * 4);
      unsigned long long b0 = __ballot(m.x != 0);
      unsigned long long b1 = __ballot(m.y != 0);
      unsigned long long b2 = __ballot(m.z != 0);
      unsigned long long b3 = __ballot(m.w != 0);
      unsigned long long v = lane == 0 ? b0 : lane == 1 ? b1 : lane == 2 ? b2 : b3;
      if (lane < 4) BM[(size_t)task * 4 + lane] = v;
    }
    return;
  }

  const int pb = blockIdx.x - 512;
  const int which = pb >> 9;
  const float* X = which == 0 ? query : (which == 1 ? key : value);
  const unsigned short* Wf = which == 0 ? Wfq : (which == 1 ? Wfk : Wfv);
  const int R0 = (pb & 511) * 16;

  const int w = tid >> 6, lane = tid & 63;
  const int g = lane >> 4, lr = lane & 15;

  f32x4 xr[16];
#pragma unroll
  for (int i = 0; i < 8; ++i) {
    int c = tid + 256 * i;
    int row = c >> 7, kc = c & 127;
    const float* src = X + (size_t)(R0 + row) * 1024 + kc * 8;
    xr[2 * i] = *(const f32x4*)src;
    xr[2 * i + 1] = *(const f32x4*)(src + 4);
  }
#pragma unroll
  for (int i = 0; i < 8; ++i) {
    int c = tid + 256 * i;
    int row = c >> 7, kc = c & 127;
    uint4 p;
    p.x = pack2bf(xr[2 * i][0], xr[2 * i][1]);
    p.y = pack2bf(xr[2 * i][2], xr[2 * i][3]);
    p.z = pack2bf(xr[2 * i + 1][0], xr[2 * i + 1][1]);
    p.w = pack2bf(xr[2 * i + 1][2], xr[2 * i + 1][3]);
    *(uint4*)&Xl[row * 1032 + kc * 8] = p;
  }
  __syncthreads();

  f32x4 acc0 = (f32x4){0.f, 0.f, 0.f, 0.f};
  f32x4 acc1 = (f32x4){0.f, 0.f, 0.f, 0.f};
  const unsigned short* xrow = &Xl[lr * 1032 + g * 8];
  const unsigned short* wfb = Wf + (size_t)(w * 4 + g) * 128 + lr * 8;
#pragma unroll
  for (int ks = 0; ks < 32; ks += 2) {
    bf16x8 a0 = *(const bf16x8*)(xrow + ks * 32);
    bf16x8 b0 = *(const bf16x8*)(wfb + (size_t)ks * 2048);
    acc0 = __builtin_amdgcn_mfma_f32_16x16x32_bf16(a0, b0, acc0, 0, 0, 0);
    bf16x8 a1 = *(const bf16x8*)(xrow + (ks + 1) * 32);
    bf16x8 b1 = *(const bf16x8*)(wfb + (size_t)(ks + 1) * 2048);
    acc1 = __builtin_amdgcn_mfma_f32_16x16x32_bf16(a1, b1, acc1, 0, 0, 0);
  }
  f32x4 acc = acc0 + acc1;

  const int dk = w * 16 + lr;
  if (which == 0) {
#pragma unroll
    for (int i = 0; i < 4; ++i)
      Qp[(size_t)(R0 + 4 * g + i) * 64 + dk] = f2bf(acc[i]);
  } else if (which == 1) {
#pragma unroll
    for (int i = 0; i < 4; ++i) {
      const int sg = R0 + 4 * g + i;
      const int b = sg >> 11, sl = sg & 2047;
      const int tile = b * 32 + (sl >> 6), c = (sl >> 4) & 3, lrk = sl & 15;
      Kf[(size_t)tile * 4096 + (c * 8 + (dk >> 3)) * 128 + lrk * 8 + (dk & 7)] = f2bf(acc[i]);
    }
  } else {
#pragma unroll
    for (int i = 0; i < 4; ++i) {
      const int sg = R0 + 4 * g + i;
      const int b = sg >> 11, sl = sg & 2047;
      const int tile = b * 32 + (sl >> 6);
      const int h = (sl >> 5) & 1, g2 = (sl >> 3) & 3, e2 = sl & 7;
      Vf[(size_t)tile * 4096 + ((w * 2 + h) * 4 + g2) * 128 + lr * 8 + e2] = f2bf(acc[i]);
    }
  }
}

// ---------------------------------------------------------------------------
// attn: no LDS, no barriers, all fragment loads coalesced; mask via bitmask.
// Opart stored in FRAGMENT ORDER: [T][t][lane][4] f32, T = gy*512 + bx*2 + w.
// Lane (g,lr)'s o[t][i] = element (row q = T*16+lr, col dk = t*16+g*4+i).
// grid (BL/32, G_SPLIT) = 2048 blocks, 128 thr.
// ---------------------------------------------------------------------------
__global__ __launch_bounds__(128, 4)
void attn_kernel(const unsigned short* __restrict__ Qp, const unsigned short* __restrict__ Kf,
                 const unsigned short* __restrict__ Vf, const unsigned long long* __restrict__ BM,
                 float* __restrict__ Opart, float* __restrict__ lpart) {
  const int q0 = blockIdx.x * 32;
  const int gy = blockIdx.y;
  const int b = q0 >> 11;
  const int tid = threadIdx.x, lane = tid & 63, w = tid >> 6;
  const int g = lane >> 4, lr = lane & 15;

  const unsigned short* qrow = Qp + (size_t)(q0 + w * 16 + lr) * 64;
  bf16x8 qf0 = *(const bf16x8*)(qrow + g * 8);
  bf16x8 qf1 = *(const bf16x8*)(qrow + 32 + g * 8);

  const unsigned long long* bm = BM + ((size_t)(q0 + w * 16 + lr) * 8 + gy) * 4;
  const unsigned long long W0 = bm[0], W1 = bm[1], W2 = bm[2], W3 = bm[3];

  f32x4 o[4];
#pragma unroll
  for (int t = 0; t < 4; ++t) o[t] = (f32x4){0.f, 0.f, 0.f, 0.f};
  float lsum = 0.f;

  const unsigned short* Kt = Kf + (size_t)(b * 32 + gy * 4) * 4096;
  const unsigned short* Vt = Vf + (size_t)(b * 32 + gy * 4) * 4096;

#pragma unroll
  for (int st = 0; st < 4; ++st) {
    const unsigned short* Kts = Kt + st * 4096;
    const unsigned short* Vts = Vt + st * 4096;

    bf16x8 kf0[4], kf1[4];
#pragma unroll
    for (int c = 0; c < 4; ++c) {
      kf0[c] = *(const bf16x8*)(Kts + (c * 8 + g) * 128 + lr * 8);
      kf1[c] = *(const bf16x8*)(Kts + (c * 8 + 4 + g) * 128 + lr * 8);
    }

    uint2 packs[4];
#pragma unroll
    for (int c = 0; c < 4; ++c) {
      f32x4 a4 = (f32x4){0.f, 0.f, 0.f, 0.f};
      a4 = __builtin_amdgcn_mfma_f32_16x16x32_bf16(kf0[c], qf0, a4, 0, 0, 0);
      a4 = __builtin_amdgcn_mfma_f32_16x16x32_bf16(kf1[c], qf1, a4, 0, 0, 0);
      const int j = st * 16 + 4 * c + g;
      float p0 = ((W0 >> j) & 1) ? __expf(a4[0] * 0.125f) : 0.f;
      float p1 = ((W1 >> j) & 1) ? __expf(a4[1] * 0.125f) : 0.f;
      float p2 = ((W2 >> j) & 1) ? __expf(a4[2] * 0.125f) : 0.f;
      float p3 = ((W3 >> j) & 1) ? __expf(a4[3] * 0.125f) : 0.f;
      lsum += (p0 + p1) + (p2 + p3);
      packs[c].x = pack2bf(p0, p1);
      packs[c].y = pack2bf(p2, p3);
    }

#pragma unroll
    for (int h = 0; h < 2; ++h) {
      const int srcLo = lr + ((g & 1) << 5);
      const int srcHi = srcLo + 16;
      uint2 pl0 = packs[2 * h], pl1 = packs[2 * h + 1];
      unsigned a0x = __shfl((int)pl0.x, srcLo), a0y = __shfl((int)pl0.y, srcLo);
      unsigned a1x = __shfl((int)pl1.x, srcLo), a1y = __shfl((int)pl1.y, srcLo);
      unsigned b0x = __shfl((int)pl0.x, srcHi), b0y = __shfl((int)pl0.y, srcHi);
      unsigned b1x = __shfl((int)pl1.x, srcHi), b1y = __shfl((int)pl1.y, srcHi);
      const bool hisel = ((g >> 1) & 1) != 0;
      uint4 bb;
      bb.x = hisel ? a1x : a0x;
      bb.y = hisel ? a1y : a0y;
      bb.z = hisel ? b1x : b0x;
      bb.w = hisel ? b1y : b0y;
      bf16x8 pb = __builtin_bit_cast(bf16x8, bb);
#pragma unroll
      for (int t = 0; t < 4; ++t) {
        bf16x8 av = *(const bf16x8*)(Vts + ((t * 2 + h) * 4 + g) * 128 + lr * 8);
        o[t] = __builtin_amdgcn_mfma_f32_16x16x32_bf16(av, pb, o[t], 0, 0, 0);
      }
    }
  }

  lsum += __shfl_xor(lsum, 16);
  lsum += __shfl_xor(lsum, 32);

  // fragment-ordered store: T = gy*512 + bx*2 + w; [T][t][lane][4] f32
  float* Ob = Opart + ((size_t)(gy * 512 + blockIdx.x * 2 + w) * 4) * 256;
#pragma unroll
  for (int t = 0; t < 4; ++t)
    *(f32x4*)(Ob + (t * 256) + lane * 4) = o[t];
  if (lane < 16)
    lpart[(size_t)gy * BL + q0 + w * 16 + lane] = lsum;
}

// ---------------------------------------------------------------------------
// oproj (combine fused): builds the Hp tile in-LDS from fragment-ordered
// Opart (tile r holds row q = r*16+lr, cols dk = t*16+g*4+i) + lpart
// normalization, then the usual MFMA.
// grid (128 m-tiles, 4 n-tiles of 256), 256 thr.
// ---------------------------------------------------------------------------
__global__ __launch_bounds__(256)
void oproj_kernel(const float* __restrict__ Opart, const float* __restrict__ lpart,
                  const unsigned short* __restrict__ WoSumT, float* __restrict__ out) {
  const int R0 = blockIdx.x * 64;
  const int n0 = blockIdx.y * 256;
  __shared__ __align__(16) unsigned short Hl[64 * 72];
  __shared__ __align__(16) unsigned short Wl[256 * 72];
  const int tid = threadIdx.x, lane = tid & 63, w = tid >> 6;
  const int g = lane >> 4, lr = lane & 15;

#pragma unroll
  for (int i = 0; i < 8; ++i) {
    int c = tid + 256 * i;
    int row = c >> 3, cc = c & 7;
    *(uint4*)&Wl[row * 72 + cc * 8] = *(const uint4*)(WoSumT + (size_t)(n0 + row) * 64 + cc * 8);
  }

  {
    const int t = w;
#pragma unroll
    for (int j = 0; j < 4; ++j) {
      const int rg = (R0 >> 4) + j;           // global tile, rows rg*16..+15
      const int q = rg * 16 + lr;
      f32x4 s = (f32x4){0.f, 0.f, 0.f, 0.f};
      float l = 0.f;
#pragma unroll
      for (int gg = 0; gg < G_SPLIT; ++gg) {
        f32x4 a = *(const f32x4*)(Opart + ((size_t)((gg * 512 + rg) * 4 + t)) * 256 + lane * 4);
        s[0] += a[0]; s[1] += a[1]; s[2] += a[2]; s[3] += a[3];
        l += lpart[(size_t)gg * BL + q];
      }
      const float inv = 1.f / l;
      uint2 pv;
      pv.x = pack2bf(s[0] * inv, s[1] * inv);
      pv.y = pack2bf(s[2] * inv, s[3] * inv);
      *(uint2*)&Hl[(j * 16 + lr) * 72 + t * 16 + g * 4] = pv;
    }
  }
  __syncthreads();

  f32x4 acc[16];
#pragma unroll
  for (int t = 0; t < 16; ++t) acc[t] = (f32x4){0.f, 0.f, 0.f, 0.f};
#pragma unroll
  for (int kh = 0; kh < 2; ++kh) {
    bf16x8 a = *(const bf16x8*)&Hl[(w * 16 + lr) * 72 + kh * 32 + g * 8];
#pragma unroll
    for (int t = 0; t < 16; ++t) {
      bf16x8 bb = *(const bf16x8*)&Wl[(t * 16 + lr) * 72 + kh * 32 + g * 8];
      acc[t] = __builtin_amdgcn_mfma_f32_16x16x32_bf16(a, bb, acc[t], 0, 0, 0);
    }
  }
  float* ob = out + (size_t)(R0 + w * 16 + g * 4) * 1024 + n0 + lr;
#pragma unroll
  for (int t = 0; t < 16; ++t)
#pragma unroll
    for (int i = 0; i < 4; ++i)
      ob[(size_t)i * 1024 + t * 16] = acc[t][i];
}

// ---------------------------------------------------------------------------
extern "C" void kernel_launch(void* const* d_in, const int* in_sizes, int n_in,
                              void* d_out, int out_size, void* d_ws, size_t ws_size,
                              hipStream_t stream) {
  const float* query = (const float*)d_in[0];
  const float* key   = (const float*)d_in[1];
  const float* value = (const float*)d_in[2];
  const int*   mask  = (const int*)d_in[3];
  const float* Wq    = (const float*)d_in[4];
  const float* Wk    = (const float*)d_in[5];
  const float* Wv    = (const float*)d_in[6];
  const float* Wo    = (const float*)d_in[7];
  float* out = (float*)d_out;

  unsigned short* Qp   = (unsigned short*)d_ws;           // 8192*64
  unsigned short* Kf   = Qp + (size_t)BL * 64;            // 8192*64 (fragment order)
  unsigned short* Vf   = Kf + (size_t)BL * 64;            // 8192*64 (fragment order)
  unsigned short* Wfq  = Vf + (size_t)BL * 64;            // 64*1024 (fragment order)
  unsigned short* Wfk  = Wfq + 65536;
  unsigned short* Wfv  = Wfk + 65536;
  unsigned short* WoSumT = Wfv + 65536;                   // 1024*64
  float* lpart = (float*)(WoSumT + 65536);                // G*8192
  float* Opart = lpart + (size_t)G_SPLIT * BL;            // G*8192*64 fp32 (fragment order)
  unsigned long long* BM = (unsigned long long*)(Opart + (size_t)G_SPLIT * BL * 64); // 2MB

  hipLaunchKernelGGL(prep_kernel, dim3(1024), dim3(256), 0, stream,
                     Wq, Wk, Wv, Wo, Wfq, Wfk, Wfv, WoSumT);
  hipLaunchKernelGGL(projmask_kernel, dim3(2048), dim3(256), 0, stream,
                     query, key, value, Wfq, Wfk, Wfv, mask, BM, Qp, Kf, Vf);
  hipLaunchKernelGGL(attn_kernel, dim3(BL / 32, G_SPLIT), dim3(128), 0, stream,
                     Qp, Kf, Vf, BM, Opart, lpart);
  hipLaunchKernelGGL(oproj_kernel, dim3(128, 4), dim3(256), 0, stream,
                     Opart, lpart, WoSumT, out);
}